// Round 2
// baseline (224.357 us; speedup 1.0000x reference)
//
#include <hip/hip_runtime.h>
#include <math.h>

#define BATCH 8
#define HH 512
#define WW 512
#define IMG (HH * WW)
#define NTOT (BATCH * IMG)
#define TROWS 16
#define TS (TROWS * WW)            // 8192 px per tile
#define NTILES (NTOT / TS)         // 256 tiles per field
#define BPF (BATCH * (HH / TROWS - 1) * WW)  // 126976 border px per field
#define THRESH 0.5f
#define FXSCALE 4294967296.0       // 2^32 fixed-point scale

// ---------- union-find helpers ----------

__device__ __forceinline__ int findroot_g(const int* p, int x) {
    int px;
    while ((px = p[x]) != x) x = px;
    return x;
}

__device__ __forceinline__ void unite_g(int* p, int a, int b) {
    bool done = false;
    do {
        a = findroot_g(p, a);
        b = findroot_g(p, b);
        if (a > b) {
            int old = atomicMin(&p[a], b);
            done = (old == a);
            a = old;
        } else if (b > a) {
            int old = atomicMin(&p[b], a);
            done = (old == b);
            b = old;
        } else {
            done = true;
        }
    } while (!done);
}

__device__ __forceinline__ int findroot_s(const int* p, int x) {
    int px;
    while ((px = p[x]) != x) x = px;
    return x;
}

__device__ __forceinline__ void unite_s(int* p, int a, int b) {
    bool done = false;
    do {
        a = findroot_s(p, a);
        b = findroot_s(p, b);
        if (a > b) {
            int old = atomicMin(&p[a], b);
            done = (old == a);
            a = old;
        } else if (b > a) {
            int old = atomicMin(&p[b], a);
            done = (old == b);
            b = old;
        } else {
            done = true;
        }
    } while (!done);
}

// ---------- kernel 1: per-tile CCL in LDS (both fields), zero flags/acc ----------

__global__ void __launch_bounds__(256) k_local(const float* __restrict__ preds,
                                               const float* __restrict__ targets,
                                               int* __restrict__ pP, int* __restrict__ pT,
                                               unsigned int* __restrict__ flagP,
                                               unsigned int* __restrict__ flagT,
                                               unsigned long long* __restrict__ acc) {
    __shared__ int lp[TS];
    int bid = blockIdx.x;
    int field = bid >> 8;       // 0 = pred, 1 = target  (NTILES==256)
    int tb = bid & 255;
    const float* __restrict__ src = field ? targets : preds;
    int* __restrict__ gp = field ? pT : pP;
    unsigned int* __restrict__ fl = field ? flagT : flagP;
    const int base = tb * TS;

    if (bid == 0 && threadIdx.x == 0) *acc = 0ull;
    // zero this tile's flag slice: TS/32 = 256 words, one per thread
    fl[(base >> 5) + threadIdx.x] = 0u;

    for (int l = threadIdx.x; l < TS; l += 256) {
        float v = src[base + l];
        bool fg = field ? (v != 0.0f) : (v > THRESH);
        lp[l] = fg ? l : -1;
    }
    __syncthreads();

    for (int l = threadIdx.x; l < TS; l += 256) {
        if (lp[l] < 0) continue;
        if ((l & (WW - 1)) != WW - 1 && lp[l + 1] >= 0) unite_s(lp, l, l + 1);
        if (l < TS - WW && lp[l + WW] >= 0) unite_s(lp, l, l + WW);
    }
    __syncthreads();

    for (int l = threadIdx.x; l < TS; l += 256) {
        int v = lp[l];
        int out = -1;
        if (v >= 0) out = base + findroot_s(lp, l);
        gp[base + l] = out;
    }
}

// ---------- kernel 2: unite across tile boundaries (global, tiny) ----------

__global__ void k_border(int* __restrict__ pP, int* __restrict__ pT) {
    int id = blockIdx.x * blockDim.x + threadIdx.x;
    if (id >= 2 * BPF) return;
    int field = (id >= BPF) ? 1 : 0;
    int r = id - field * BPF;
    int* p = field ? pT : pP;
    const int perimg = (HH / TROWS - 1) * WW;   // 15872
    int img = r / perimg;
    int rem = r - img * perimg;
    int b = rem >> 9;
    int c = rem & (WW - 1);
    int row = b * TROWS + (TROWS - 1);
    int n = img * IMG + row * WW + c;
    if (p[n] >= 0 && p[n + WW] >= 0) unite_g(p, n, n + WW);
}

// ---------- kernel 3: flatten parents + mark critical roots in flag bitmaps ----------

__global__ void k_flatmark(const float* __restrict__ preds, const float* __restrict__ targets,
                           int* __restrict__ pP, int* __restrict__ pT,
                           unsigned int* __restrict__ flagP, unsigned int* __restrict__ flagT) {
    int n = blockIdx.x * blockDim.x + threadIdx.x;
    if (n >= NTOT) return;
    bool fp = preds[n] > THRESH;
    bool ft = targets[n] != 0.0f;
    if (fp) {
        int r = findroot_g(pP, n);
        if (pP[n] != r) pP[n] = r;
        if (!ft) atomicOr(&flagP[r >> 5], 1u << (r & 31));
    }
    if (ft) {
        int r = findroot_g(pT, n);
        if (pT[n] != r) pT[n] = r;
        if (!fp) atomicOr(&flagT[r >> 5], 1u << (r & 31));
    }
}

// ---------- kernel 4: loss + mask blend + deterministic fixed-point reduce ----------

__device__ __forceinline__ float softplusf(float z) {
    return fmaxf(z, 0.0f) + log1pf(expf(-fabsf(z)));
}

__device__ __forceinline__ float block_reduce_sum(float v, float* smem4) {
    for (int off = 32; off > 0; off >>= 1) v += __shfl_down(v, off, 64);
    int lane = threadIdx.x & 63, wid = threadIdx.x >> 6;
    if (lane == 0) smem4[wid] = v;
    __syncthreads();
    return smem4[0] + smem4[1] + smem4[2] + smem4[3];
}

__global__ void k_gather(const float* __restrict__ preds, const float* __restrict__ targets,
                         const int* __restrict__ pP, const int* __restrict__ pT,
                         const unsigned int* __restrict__ flagP,
                         const unsigned int* __restrict__ flagT,
                         unsigned long long* __restrict__ acc) {
    int n = blockIdx.x * blockDim.x + threadIdx.x;
    float contrib = 0.0f;
    if (n < NTOT) {
        float x = preds[n];
        float t = targets[n];
        float loss = t * softplusf(-x) + (1.0f - t) * softplusf(x);
        bool fp = x > THRESH;
        bool ft = t != 0.0f;
        float m = 0.0f;
        if (ft) {
            int r = pT[n];
            if ((flagT[r >> 5] >> (r & 31)) & 1u) m += 0.5f;   // BETA * neg
        }
        if (fp) {
            int r = pP[n];
            if ((flagP[r >> 5] >> (r & 31)) & 1u) m += 0.5f;   // (1-BETA) * pos
        }
        contrib = (0.5f + 0.5f * m) * loss;                    // (1-a)L + a*m*L, a=0.5
    }
    __shared__ float smem4[4];
    float s = block_reduce_sum(contrib, smem4);
    if (threadIdx.x == 0) {
        long long q = (long long)((double)s * FXSCALE);
        atomicAdd(acc, (unsigned long long)q);
    }
}

__global__ void k_final(const unsigned long long* __restrict__ acc, float* __restrict__ out) {
    if (threadIdx.x == 0)
        out[0] = (float)((double)(long long)(*acc) / (FXSCALE * (double)NTOT));
}

// ---------- launch ----------

extern "C" void kernel_launch(void* const* d_in, const int* in_sizes, int n_in,
                              void* d_out, int out_size, void* d_ws, size_t ws_size,
                              hipStream_t stream) {
    const float* preds = (const float*)d_in[0];
    const float* targets = (const float*)d_in[1];

    int* pP = (int*)d_ws;                              // 8 MB
    int* pT = pP + NTOT;                               // 8 MB
    unsigned int* flagP = (unsigned int*)(pT + NTOT);  // 256 KB
    unsigned int* flagT = flagP + (NTOT >> 5);         // 256 KB
    unsigned long long* acc = (unsigned long long*)(flagT + (NTOT >> 5));
    float* out = (float*)d_out;

    const int block = 256;

    k_local<<<2 * NTILES, block, 0, stream>>>(preds, targets, pP, pT, flagP, flagT, acc);
    k_border<<<(2 * BPF + block - 1) / block, block, 0, stream>>>(pP, pT);
    k_flatmark<<<(NTOT + block - 1) / block, block, 0, stream>>>(preds, targets, pP, pT, flagP, flagT);
    k_gather<<<(NTOT + block - 1) / block, block, 0, stream>>>(preds, targets, pP, pT, flagP, flagT, acc);
    k_final<<<1, 64, 0, stream>>>(acc, out);
}

// Round 3
// 144.187 us; speedup vs baseline: 1.5560x; 1.5560x over previous
//
#include <hip/hip_runtime.h>
#include <math.h>

#define BATCH 8
#define HH 512
#define WW 512
#define IMG (HH * WW)
#define NTOT (BATCH * IMG)
#define TROWS 16
#define TS (TROWS * WW)            // 8192 px per tile
#define NTILES (NTOT / TS)         // 256 tiles per field
#define BPF (BATCH * (HH / TROWS - 1) * WW)  // 126976 border px per field
#define THRESH 0.5f
#define NBLK (NTOT / 256)          // 8192 gather blocks

// ---------- union-find helpers ----------

__device__ __forceinline__ int findroot_g(const int* p, int x) {
    int px;
    while ((px = p[x]) != x) x = px;
    return x;
}

__device__ __forceinline__ void unite_g(int* p, int a, int b) {
    bool done = false;
    do {
        a = findroot_g(p, a);
        b = findroot_g(p, b);
        if (a > b) {
            int old = atomicMin(&p[a], b);
            done = (old == a);
            a = old;
        } else if (b > a) {
            int old = atomicMin(&p[b], a);
            done = (old == b);
            b = old;
        } else {
            done = true;
        }
    } while (!done);
}

__device__ __forceinline__ int findroot_s(const int* p, int x) {
    int px;
    while ((px = p[x]) != x) x = px;
    return x;
}

__device__ __forceinline__ void unite_s(int* p, int a, int b) {
    bool done = false;
    do {
        a = findroot_s(p, a);
        b = findroot_s(p, b);
        if (a > b) {
            int old = atomicMin(&p[a], b);
            done = (old == a);
            a = old;
        } else if (b > a) {
            int old = atomicMin(&p[b], a);
            done = (old == b);
            b = old;
        } else {
            done = true;
        }
    } while (!done);
}

// ---------- kernel 1: per-tile CCL in LDS (both fields), zero flag bitmaps ----------

__global__ void __launch_bounds__(256) k_local(const float* __restrict__ preds,
                                               const float* __restrict__ targets,
                                               int* __restrict__ pP, int* __restrict__ pT,
                                               unsigned int* __restrict__ flagP,
                                               unsigned int* __restrict__ flagT) {
    __shared__ int lp[TS];
    int bid = blockIdx.x;
    int field = bid >> 8;       // 0 = pred, 1 = target  (NTILES==256)
    int tb = bid & 255;
    const float* __restrict__ src = field ? targets : preds;
    int* __restrict__ gp = field ? pT : pP;
    unsigned int* __restrict__ fl = field ? flagT : flagP;
    const int base = tb * TS;

    // zero this tile's flag slice: TS/32 = 256 words, one per thread
    fl[(base >> 5) + threadIdx.x] = 0u;

    for (int l = threadIdx.x; l < TS; l += 256) {
        float v = src[base + l];
        bool fg = field ? (v != 0.0f) : (v > THRESH);
        lp[l] = fg ? l : -1;
    }
    __syncthreads();

    for (int l = threadIdx.x; l < TS; l += 256) {
        if (lp[l] < 0) continue;
        if ((l & (WW - 1)) != WW - 1 && lp[l + 1] >= 0) unite_s(lp, l, l + 1);
        if (l < TS - WW && lp[l + WW] >= 0) unite_s(lp, l, l + WW);
    }
    __syncthreads();

    for (int l = threadIdx.x; l < TS; l += 256) {
        int v = lp[l];
        int out = -1;
        if (v >= 0) out = base + findroot_s(lp, l);
        gp[base + l] = out;
    }
}

// ---------- kernel 2: unite across tile boundaries (global, tiny) ----------

__global__ void k_border(int* __restrict__ pP, int* __restrict__ pT) {
    int id = blockIdx.x * blockDim.x + threadIdx.x;
    if (id >= 2 * BPF) return;
    int field = (id >= BPF) ? 1 : 0;
    int r = id - field * BPF;
    int* p = field ? pT : pP;
    const int perimg = (HH / TROWS - 1) * WW;   // 15872
    int img = r / perimg;
    int rem = r - img * perimg;
    int b = rem >> 9;
    int c = rem & (WW - 1);
    int row = b * TROWS + (TROWS - 1);
    int n = img * IMG + row * WW + c;
    if (p[n] >= 0 && p[n + WW] >= 0) unite_g(p, n, n + WW);
}

// ---------- kernel 3: flatten parents + mark critical roots in flag bitmaps ----------

__global__ void k_flatmark(const float* __restrict__ preds, const float* __restrict__ targets,
                           int* __restrict__ pP, int* __restrict__ pT,
                           unsigned int* __restrict__ flagP, unsigned int* __restrict__ flagT) {
    int n = blockIdx.x * blockDim.x + threadIdx.x;
    if (n >= NTOT) return;
    bool fp = preds[n] > THRESH;
    bool ft = targets[n] != 0.0f;
    if (fp) {
        int r = findroot_g(pP, n);
        if (pP[n] != r) pP[n] = r;
        if (!ft) atomicOr(&flagP[r >> 5], 1u << (r & 31));
    }
    if (ft) {
        int r = findroot_g(pT, n);
        if (pT[n] != r) pT[n] = r;
        if (!fp) atomicOr(&flagT[r >> 5], 1u << (r & 31));
    }
}

// ---------- kernel 4: loss + mask blend + per-block partial (deterministic) ----------

__device__ __forceinline__ float softplusf(float z) {
    return fmaxf(z, 0.0f) + log1pf(expf(-fabsf(z)));
}

__device__ __forceinline__ float block_reduce_sum(float v, float* smem4) {
    for (int off = 32; off > 0; off >>= 1) v += __shfl_down(v, off, 64);
    int lane = threadIdx.x & 63, wid = threadIdx.x >> 6;
    if (lane == 0) smem4[wid] = v;
    __syncthreads();
    return smem4[0] + smem4[1] + smem4[2] + smem4[3];
}

__global__ void k_gather(const float* __restrict__ preds, const float* __restrict__ targets,
                         const int* __restrict__ pP, const int* __restrict__ pT,
                         const unsigned int* __restrict__ flagP,
                         const unsigned int* __restrict__ flagT,
                         float* __restrict__ partial) {
    int n = blockIdx.x * blockDim.x + threadIdx.x;
    float contrib = 0.0f;
    if (n < NTOT) {
        float x = preds[n];
        float t = targets[n];
        float loss = t * softplusf(-x) + (1.0f - t) * softplusf(x);
        bool fp = x > THRESH;
        bool ft = t != 0.0f;
        float m = 0.0f;
        if (ft) {
            int r = pT[n];
            if ((flagT[r >> 5] >> (r & 31)) & 1u) m += 0.5f;   // BETA * neg
        }
        if (fp) {
            int r = pP[n];
            if ((flagP[r >> 5] >> (r & 31)) & 1u) m += 0.5f;   // (1-BETA) * pos
        }
        contrib = (0.5f + 0.5f * m) * loss;                    // (1-a)L + a*m*L, a=0.5
    }
    __shared__ float smem4[4];
    float s = block_reduce_sum(contrib, smem4);
    if (threadIdx.x == 0) partial[blockIdx.x] = s;
}

__global__ void k_final(const float* __restrict__ partial, float* __restrict__ out) {
    float s = 0.0f;
    for (int i = threadIdx.x; i < NBLK; i += 256) s += partial[i];
    __shared__ float smem4[4];
    float tot = block_reduce_sum(s, smem4);
    if (threadIdx.x == 0) out[0] = tot / (float)NTOT;
}

// ---------- launch ----------

extern "C" void kernel_launch(void* const* d_in, const int* in_sizes, int n_in,
                              void* d_out, int out_size, void* d_ws, size_t ws_size,
                              hipStream_t stream) {
    const float* preds = (const float*)d_in[0];
    const float* targets = (const float*)d_in[1];

    int* pP = (int*)d_ws;                              // 8 MB
    int* pT = pP + NTOT;                               // 8 MB
    unsigned int* flagP = (unsigned int*)(pT + NTOT);  // 256 KB
    unsigned int* flagT = flagP + (NTOT >> 5);         // 256 KB
    float* partial = (float*)(flagT + (NTOT >> 5));    // 32 KB
    float* out = (float*)d_out;

    const int block = 256;

    k_local<<<2 * NTILES, block, 0, stream>>>(preds, targets, pP, pT, flagP, flagT);
    k_border<<<(2 * BPF + block - 1) / block, block, 0, stream>>>(pP, pT);
    k_flatmark<<<(NTOT + block - 1) / block, block, 0, stream>>>(preds, targets, pP, pT, flagP, flagT);
    k_gather<<<(NTOT + block - 1) / block, block, 0, stream>>>(preds, targets, pP, pT, flagP, flagT, partial);
    k_final<<<1, 256, 0, stream>>>(partial, out);
}

// Round 4
// 115.331 us; speedup vs baseline: 1.9453x; 1.2502x over previous
//
#include <hip/hip_runtime.h>
#include <math.h>

#define BATCH 8
#define HH 512
#define WW 512
#define IMG (HH * WW)
#define NTOT (BATCH * IMG)
#define TROWS 4
#define TS (TROWS * WW)                      // 2048 px per tile (8 KB LDS)
#define NTILES (NTOT / TS)                   // 1024 tiles per field
#define BPF (BATCH * (HH / TROWS - 1) * WW)  // 520192 border px per field
#define THRESH 0.5f
#define NBLK (NTOT / 256)                    // 8192 gather blocks

// ---------- union-find helpers (finds are read-only: safe vs concurrent atomicMin) ----------

__device__ __forceinline__ int findroot_g(const int* p, int x) {
    int px;
    while ((px = p[x]) != x) x = px;
    return x;
}

__device__ __forceinline__ void unite_g(int* p, int a, int b) {
    bool done = false;
    do {
        a = findroot_g(p, a);
        b = findroot_g(p, b);
        if (a > b) {
            int old = atomicMin(&p[a], b);
            done = (old == a);
            a = old;
        } else if (b > a) {
            int old = atomicMin(&p[b], a);
            done = (old == b);
            b = old;
        } else {
            done = true;
        }
    } while (!done);
}

__device__ __forceinline__ int findroot_s(const int* p, int x) {
    int px;
    while ((px = p[x]) != x) x = px;
    return x;
}

__device__ __forceinline__ void unite_s(int* p, int a, int b) {
    bool done = false;
    do {
        a = findroot_s(p, a);
        b = findroot_s(p, b);
        if (a > b) {
            int old = atomicMin(&p[a], b);
            done = (old == a);
            a = old;
        } else if (b > a) {
            int old = atomicMin(&p[b], a);
            done = (old == b);
            b = old;
        } else {
            done = true;
        }
    } while (!done);
}

// ---------- kernel 1: per-tile CCL in LDS (both fields), zero flag bitmaps ----------

__global__ void __launch_bounds__(256) k_local(const float* __restrict__ preds,
                                               const float* __restrict__ targets,
                                               int* __restrict__ pP, int* __restrict__ pT,
                                               unsigned int* __restrict__ flagP,
                                               unsigned int* __restrict__ flagT) {
    __shared__ int lp[TS];
    int bid = blockIdx.x;
    int field = bid >> 10;                   // 0 = pred, 1 = target (NTILES==1024)
    int tb = bid & (NTILES - 1);
    const float* __restrict__ src = field ? targets : preds;
    int* __restrict__ gp = field ? pT : pP;
    unsigned int* __restrict__ fl = field ? flagT : flagP;
    const int base = tb * TS;

    // zero this tile's flag slice: TS/32 = 64 words
    if (threadIdx.x < TS / 32) fl[(base >> 5) + threadIdx.x] = 0u;

    // vectorized init: 2 float4 per thread
    const float4* __restrict__ src4 = (const float4*)(src + base);
    for (int i = threadIdx.x; i < TS / 4; i += 256) {
        float4 v = src4[i];
        int l = 4 * i;
        if (field) {
            lp[l]     = (v.x != 0.0f) ? l     : -1;
            lp[l + 1] = (v.y != 0.0f) ? l + 1 : -1;
            lp[l + 2] = (v.z != 0.0f) ? l + 2 : -1;
            lp[l + 3] = (v.w != 0.0f) ? l + 3 : -1;
        } else {
            lp[l]     = (v.x > THRESH) ? l     : -1;
            lp[l + 1] = (v.y > THRESH) ? l + 1 : -1;
            lp[l + 2] = (v.z > THRESH) ? l + 2 : -1;
            lp[l + 3] = (v.w > THRESH) ? l + 3 : -1;
        }
    }
    __syncthreads();

    // union: right + down, 8 px per thread
    for (int l = threadIdx.x; l < TS; l += 256) {
        if (lp[l] < 0) continue;
        if ((l & (WW - 1)) != WW - 1 && lp[l + 1] >= 0) unite_s(lp, l, l + 1);
        if (l < TS - WW && lp[l + WW] >= 0) unite_s(lp, l, l + WW);
    }
    __syncthreads();

    // flatten to global ids, coalesced write
    for (int l = threadIdx.x; l < TS; l += 256) {
        int out = -1;
        if (lp[l] >= 0) out = base + findroot_s(lp, l);
        gp[base + l] = out;
    }
}

// ---------- kernel 2: unite across tile boundaries (global) ----------

__global__ void k_border(int* __restrict__ pP, int* __restrict__ pT) {
    int id = blockIdx.x * blockDim.x + threadIdx.x;
    if (id >= 2 * BPF) return;
    int field = (id >= BPF) ? 1 : 0;
    int r = id - field * BPF;
    int* p = field ? pT : pP;
    const int perimg = (HH / TROWS - 1) * WW;   // 65024
    int img = r / perimg;
    int rem = r - img * perimg;
    int b = rem >> 9;
    int c = rem & (WW - 1);
    int row = b * TROWS + (TROWS - 1);
    int n = img * IMG + row * WW + c;
    if (p[n] >= 0 && p[n + WW] >= 0) unite_g(p, n, n + WW);
}

// ---------- kernel 3: flatten parents + mark critical roots (fg from parent sign) ----------

__global__ void k_flatmark(int* __restrict__ pP, int* __restrict__ pT,
                           unsigned int* __restrict__ flagP, unsigned int* __restrict__ flagT) {
    int n = blockIdx.x * blockDim.x + threadIdx.x;
    if (n >= NTOT) return;
    int a = pP[n];
    int b = pT[n];
    bool fp = a >= 0;
    bool ft = b >= 0;
    if (fp) {
        int r = a, pr;
        while ((pr = pP[r]) != r) r = pr;
        if (a != r) pP[n] = r;
        if (!ft) atomicOr(&flagP[r >> 5], 1u << (r & 31));
    }
    if (ft) {
        int r = b, pr;
        while ((pr = pT[r]) != r) r = pr;
        if (b != r) pT[n] = r;
        if (!fp) atomicOr(&flagT[r >> 5], 1u << (r & 31));
    }
}

// ---------- kernel 4: loss + mask blend + per-block partial (deterministic) ----------

__device__ __forceinline__ float softplusf(float z) {
    return fmaxf(z, 0.0f) + log1pf(expf(-fabsf(z)));
}

__device__ __forceinline__ float block_reduce_sum(float v, float* smem4) {
    for (int off = 32; off > 0; off >>= 1) v += __shfl_down(v, off, 64);
    int lane = threadIdx.x & 63, wid = threadIdx.x >> 6;
    if (lane == 0) smem4[wid] = v;
    __syncthreads();
    return smem4[0] + smem4[1] + smem4[2] + smem4[3];
}

__global__ void k_gather(const float* __restrict__ preds, const float* __restrict__ targets,
                         const int* __restrict__ pP, const int* __restrict__ pT,
                         const unsigned int* __restrict__ flagP,
                         const unsigned int* __restrict__ flagT,
                         float* __restrict__ partial) {
    int n = blockIdx.x * blockDim.x + threadIdx.x;
    float contrib = 0.0f;
    if (n < NTOT) {
        float x = preds[n];
        float t = targets[n];
        float loss = t * softplusf(-x) + (1.0f - t) * softplusf(x);
        int a = pP[n];
        int b = pT[n];
        float m = 0.0f;
        if (b >= 0) {
            if ((flagT[b >> 5] >> (b & 31)) & 1u) m += 0.5f;   // BETA * neg
        }
        if (a >= 0) {
            if ((flagP[a >> 5] >> (a & 31)) & 1u) m += 0.5f;   // (1-BETA) * pos
        }
        contrib = (0.5f + 0.5f * m) * loss;                    // (1-a)L + a*m*L, a=0.5
    }
    __shared__ float smem4[4];
    float s = block_reduce_sum(contrib, smem4);
    if (threadIdx.x == 0) partial[blockIdx.x] = s;
}

__global__ void k_final(const float* __restrict__ partial, float* __restrict__ out) {
    float s = 0.0f;
    for (int i = threadIdx.x; i < NBLK; i += 256) s += partial[i];
    __shared__ float smem4[4];
    float tot = block_reduce_sum(s, smem4);
    if (threadIdx.x == 0) out[0] = tot / (float)NTOT;
}

// ---------- launch ----------

extern "C" void kernel_launch(void* const* d_in, const int* in_sizes, int n_in,
                              void* d_out, int out_size, void* d_ws, size_t ws_size,
                              hipStream_t stream) {
    const float* preds = (const float*)d_in[0];
    const float* targets = (const float*)d_in[1];

    int* pP = (int*)d_ws;                              // 8 MB
    int* pT = pP + NTOT;                               // 8 MB
    unsigned int* flagP = (unsigned int*)(pT + NTOT);  // 256 KB
    unsigned int* flagT = flagP + (NTOT >> 5);         // 256 KB
    float* partial = (float*)(flagT + (NTOT >> 5));    // 32 KB
    float* out = (float*)d_out;

    const int block = 256;

    k_local<<<2 * NTILES, block, 0, stream>>>(preds, targets, pP, pT, flagP, flagT);
    k_border<<<(2 * BPF + block - 1) / block, block, 0, stream>>>(pP, pT);
    k_flatmark<<<(NTOT + block - 1) / block, block, 0, stream>>>(pP, pT, flagP, flagT);
    k_gather<<<(NTOT + block - 1) / block, block, 0, stream>>>(preds, targets, pP, pT, flagP, flagT, partial);
    k_final<<<1, 256, 0, stream>>>(partial, out);
}

// Round 5
// 86.701 us; speedup vs baseline: 2.5877x; 1.3302x over previous
//
#include <hip/hip_runtime.h>
#include <math.h>

#define BATCH 8
#define HH 512
#define WW 512
#define IMG (HH * WW)
#define NTOT (BATCH * IMG)
#define TROWS 4
#define TS (TROWS * WW)                      // 2048 px per tile (8 KB LDS)
#define NTILES (NTOT / TS)                   // 1024 tiles per field
#define BPF (BATCH * (HH / TROWS - 1) * WW)  // 520192 border px per field
#define THRESH 0.5f
#define NBLK (NTOT / 256)                    // 8192 gather blocks

// ---------- union-find helpers (finds are read-only: safe vs concurrent atomicMin) ----------

__device__ __forceinline__ int findroot_g(const int* p, int x) {
    int px;
    while ((px = p[x]) != x) x = px;
    return x;
}

__device__ __forceinline__ void unite_g(int* p, int a, int b) {
    bool done = false;
    do {
        a = findroot_g(p, a);
        b = findroot_g(p, b);
        if (a > b) {
            int old = atomicMin(&p[a], b);
            done = (old == a);
            a = old;
        } else if (b > a) {
            int old = atomicMin(&p[b], a);
            done = (old == b);
            b = old;
        } else {
            done = true;
        }
    } while (!done);
}

__device__ __forceinline__ int findroot_s(const int* p, int x) {
    int px;
    while ((px = p[x]) != x) x = px;
    return x;
}

__device__ __forceinline__ void unite_s(int* p, int a, int b) {
    bool done = false;
    do {
        a = findroot_s(p, a);
        b = findroot_s(p, b);
        if (a > b) {
            int old = atomicMin(&p[a], b);
            done = (old == a);
            a = old;
        } else if (b > a) {
            int old = atomicMin(&p[b], a);
            done = (old == b);
            b = old;
        } else {
            done = true;
        }
    } while (!done);
}

// ---------- kernel 1: per-tile CCL in LDS (both fields) ----------

__global__ void __launch_bounds__(256) k_local(const float* __restrict__ preds,
                                               const float* __restrict__ targets,
                                               int* __restrict__ pP, int* __restrict__ pT) {
    __shared__ int lp[TS];
    int bid = blockIdx.x;
    int field = bid >> 10;                   // 0 = pred, 1 = target (NTILES==1024)
    int tb = bid & (NTILES - 1);
    const float* __restrict__ src = field ? targets : preds;
    int* __restrict__ gp = field ? pT : pP;
    const int base = tb * TS;

    // vectorized init: 2 float4 per thread
    const float4* __restrict__ src4 = (const float4*)(src + base);
    for (int i = threadIdx.x; i < TS / 4; i += 256) {
        float4 v = src4[i];
        int l = 4 * i;
        if (field) {
            lp[l]     = (v.x != 0.0f) ? l     : -1;
            lp[l + 1] = (v.y != 0.0f) ? l + 1 : -1;
            lp[l + 2] = (v.z != 0.0f) ? l + 2 : -1;
            lp[l + 3] = (v.w != 0.0f) ? l + 3 : -1;
        } else {
            lp[l]     = (v.x > THRESH) ? l     : -1;
            lp[l + 1] = (v.y > THRESH) ? l + 1 : -1;
            lp[l + 2] = (v.z > THRESH) ? l + 2 : -1;
            lp[l + 3] = (v.w > THRESH) ? l + 3 : -1;
        }
    }
    __syncthreads();

    // union: right + down, 8 px per thread
    for (int l = threadIdx.x; l < TS; l += 256) {
        if (lp[l] < 0) continue;
        if ((l & (WW - 1)) != WW - 1 && lp[l + 1] >= 0) unite_s(lp, l, l + 1);
        if (l < TS - WW && lp[l + WW] >= 0) unite_s(lp, l, l + WW);
    }
    __syncthreads();

    // flatten to global ids, coalesced write
    for (int l = threadIdx.x; l < TS; l += 256) {
        int out = -1;
        if (lp[l] >= 0) out = base + findroot_s(lp, l);
        gp[base + l] = out;
    }
}

// ---------- kernel 2: unite across tile boundaries (global) ----------

__global__ void k_border(int* __restrict__ pP, int* __restrict__ pT) {
    int id = blockIdx.x * blockDim.x + threadIdx.x;
    if (id >= 2 * BPF) return;
    int field = (id >= BPF) ? 1 : 0;
    int r = id - field * BPF;
    int* p = field ? pT : pP;
    const int perimg = (HH / TROWS - 1) * WW;   // 65024
    int img = r / perimg;
    int rem = r - img * perimg;
    int b = rem >> 9;
    int c = rem & (WW - 1);
    int row = b * TROWS + (TROWS - 1);
    int n = img * IMG + row * WW + c;
    if (p[n] >= 0 && p[n + WW] >= 0) unite_g(p, n, n + WW);
}

// ---------- kernel 3: flatten parents + mark critical roots (plain byte stores, no RMW) ----------

__global__ void k_flatmark(int* __restrict__ pP, int* __restrict__ pT,
                           unsigned char* __restrict__ flagP8,
                           unsigned char* __restrict__ flagT8) {
    int n = blockIdx.x * blockDim.x + threadIdx.x;
    if (n >= NTOT) return;
    int a = pP[n];
    int b = pT[n];
    bool fp = a >= 0;
    bool ft = b >= 0;
    if (fp) {
        int r = a, pr;
        while ((pr = pP[r]) != r) r = pr;
        if (a != r) pP[n] = r;
        if (!ft) flagP8[r] = 1;   // same-value races benign, no RMW
    }
    if (ft) {
        int r = b, pr;
        while ((pr = pT[r]) != r) r = pr;
        if (b != r) pT[n] = r;
        if (!fp) flagT8[r] = 1;
    }
}

// ---------- kernel 4: loss + mask blend + per-block partial (deterministic) ----------

__device__ __forceinline__ float softplusf(float z) {
    return fmaxf(z, 0.0f) + log1pf(expf(-fabsf(z)));
}

__device__ __forceinline__ float block_reduce_sum(float v, float* smem4) {
    for (int off = 32; off > 0; off >>= 1) v += __shfl_down(v, off, 64);
    int lane = threadIdx.x & 63, wid = threadIdx.x >> 6;
    if (lane == 0) smem4[wid] = v;
    __syncthreads();
    return smem4[0] + smem4[1] + smem4[2] + smem4[3];
}

__global__ void k_gather(const float* __restrict__ preds, const float* __restrict__ targets,
                         const int* __restrict__ pP, const int* __restrict__ pT,
                         const unsigned char* __restrict__ flagP8,
                         const unsigned char* __restrict__ flagT8,
                         float* __restrict__ partial) {
    int n = blockIdx.x * blockDim.x + threadIdx.x;
    float contrib = 0.0f;
    if (n < NTOT) {
        float x = preds[n];
        float t = targets[n];
        float loss = t * softplusf(-x) + (1.0f - t) * softplusf(x);
        int a = pP[n];   // final root after k_flatmark compression
        int b = pT[n];
        float m = 0.0f;
        if (b >= 0 && flagT8[b]) m += 0.5f;   // BETA * neg
        if (a >= 0 && flagP8[a]) m += 0.5f;   // (1-BETA) * pos
        contrib = (0.5f + 0.5f * m) * loss;   // (1-a)L + a*m*L, a=0.5
    }
    __shared__ float smem4[4];
    float s = block_reduce_sum(contrib, smem4);
    if (threadIdx.x == 0) partial[blockIdx.x] = s;
}

__global__ void k_final(const float* __restrict__ partial, float* __restrict__ out) {
    float s = 0.0f;
    for (int i = threadIdx.x; i < NBLK; i += 256) s += partial[i];
    __shared__ float smem4[4];
    float tot = block_reduce_sum(s, smem4);
    if (threadIdx.x == 0) out[0] = tot / (float)NTOT;
}

// ---------- launch ----------

extern "C" void kernel_launch(void* const* d_in, const int* in_sizes, int n_in,
                              void* d_out, int out_size, void* d_ws, size_t ws_size,
                              hipStream_t stream) {
    const float* preds = (const float*)d_in[0];
    const float* targets = (const float*)d_in[1];

    int* pP = (int*)d_ws;                              // 8 MB
    int* pT = pP + NTOT;                               // 8 MB
    unsigned char* flagP8 = (unsigned char*)(pT + NTOT);  // 2 MB
    unsigned char* flagT8 = flagP8 + NTOT;                // 2 MB
    float* partial = (float*)(flagT8 + NTOT);             // 32 KB
    float* out = (float*)d_out;

    const int block = 256;

    hipMemsetAsync(flagP8, 0, 2 * NTOT, stream);  // zero both flag byte arrays

    k_local<<<2 * NTILES, block, 0, stream>>>(preds, targets, pP, pT);
    k_border<<<(2 * BPF + block - 1) / block, block, 0, stream>>>(pP, pT);
    k_flatmark<<<(NTOT + block - 1) / block, block, 0, stream>>>(pP, pT, flagP8, flagT8);
    k_gather<<<(NTOT + block - 1) / block, block, 0, stream>>>(preds, targets, pP, pT, flagP8, flagT8, partial);
    k_final<<<1, 256, 0, stream>>>(partial, out);
}

// Round 6
// 82.138 us; speedup vs baseline: 2.7315x; 1.0556x over previous
//
#include <hip/hip_runtime.h>
#include <math.h>

#define BATCH 8
#define HH 512
#define WW 512
#define IMG (HH * WW)
#define NTOT (BATCH * IMG)
#define TROWS 4
#define TS (TROWS * WW)                      // 2048 px per tile (8 KB LDS)
#define NTILES (NTOT / TS)                   // 1024 tiles per field
#define BPF (BATCH * (HH / TROWS - 1) * WW)  // 520192 border px per field
#define THRESH 0.5f
#define NBLK (NTOT / 256)                    // 8192 gather blocks

// ---------- union-find helpers (finds are read-only: safe vs concurrent atomicMin) ----------

__device__ __forceinline__ int findroot_g(const int* p, int x) {
    int px;
    while ((px = p[x]) != x) x = px;
    return x;
}

__device__ __forceinline__ void unite_g(int* p, int a, int b) {
    bool done = false;
    do {
        a = findroot_g(p, a);
        b = findroot_g(p, b);
        if (a > b) {
            int old = atomicMin(&p[a], b);
            done = (old == a);
            a = old;
        } else if (b > a) {
            int old = atomicMin(&p[b], a);
            done = (old == b);
            b = old;
        } else {
            done = true;
        }
    } while (!done);
}

__device__ __forceinline__ int findroot_s(const int* p, int x) {
    int px;
    while ((px = p[x]) != x) x = px;
    return x;
}

__device__ __forceinline__ void unite_s(int* p, int a, int b) {
    bool done = false;
    do {
        a = findroot_s(p, a);
        b = findroot_s(p, b);
        if (a > b) {
            int old = atomicMin(&p[a], b);
            done = (old == a);
            a = old;
        } else if (b > a) {
            int old = atomicMin(&p[b], a);
            done = (old == b);
            b = old;
        } else {
            done = true;
        }
    } while (!done);
}

// ---------- kernel 1: per-tile CCL in LDS (both fields) + zero flag arrays ----------

__global__ void __launch_bounds__(256) k_local(const float* __restrict__ preds,
                                               const float* __restrict__ targets,
                                               int* __restrict__ pP, int* __restrict__ pT,
                                               unsigned long long* __restrict__ flags64) {
    __shared__ int lp[TS];
    int bid = blockIdx.x;
    int field = bid >> 10;                   // 0 = pred, 1 = target (NTILES==1024)
    int tb = bid & (NTILES - 1);
    const float* __restrict__ src = field ? targets : preds;
    int* __restrict__ gp = field ? pT : pP;
    const int base = tb * TS;

    // zero flag bytes: grid is 2048*256 threads, flag region is 4 MB = 524288 u64
    flags64[bid * 256 + threadIdx.x] = 0ull;

    // vectorized init: 2 float4 per thread
    const float4* __restrict__ src4 = (const float4*)(src + base);
    for (int i = threadIdx.x; i < TS / 4; i += 256) {
        float4 v = src4[i];
        int l = 4 * i;
        if (field) {
            lp[l]     = (v.x != 0.0f) ? l     : -1;
            lp[l + 1] = (v.y != 0.0f) ? l + 1 : -1;
            lp[l + 2] = (v.z != 0.0f) ? l + 2 : -1;
            lp[l + 3] = (v.w != 0.0f) ? l + 3 : -1;
        } else {
            lp[l]     = (v.x > THRESH) ? l     : -1;
            lp[l + 1] = (v.y > THRESH) ? l + 1 : -1;
            lp[l + 2] = (v.z > THRESH) ? l + 2 : -1;
            lp[l + 3] = (v.w > THRESH) ? l + 3 : -1;
        }
    }
    __syncthreads();

    // union: right + down, 8 px per thread
    for (int l = threadIdx.x; l < TS; l += 256) {
        if (lp[l] < 0) continue;
        if ((l & (WW - 1)) != WW - 1 && lp[l + 1] >= 0) unite_s(lp, l, l + 1);
        if (l < TS - WW && lp[l + WW] >= 0) unite_s(lp, l, l + WW);
    }
    __syncthreads();

    // flatten to global ids, coalesced write
    for (int l = threadIdx.x; l < TS; l += 256) {
        int out = -1;
        if (lp[l] >= 0) out = base + findroot_s(lp, l);
        gp[base + l] = out;
    }
}

// ---------- kernel 2: unite across tile boundaries (global) ----------

__global__ void k_border(int* __restrict__ pP, int* __restrict__ pT) {
    int id = blockIdx.x * blockDim.x + threadIdx.x;
    if (id >= 2 * BPF) return;
    int field = (id >= BPF) ? 1 : 0;
    int r = id - field * BPF;
    int* p = field ? pT : pP;
    const int perimg = (HH / TROWS - 1) * WW;   // 65024
    int img = r / perimg;
    int rem = r - img * perimg;
    int b = rem >> 9;
    int c = rem & (WW - 1);
    int row = b * TROWS + (TROWS - 1);
    int n = img * IMG + row * WW + c;
    if (p[n] >= 0 && p[n + WW] >= 0) unite_g(p, n, n + WW);
}

// ---------- kernel 3: flatten parents + mark critical roots (plain byte stores, no RMW) ----------

__global__ void k_flatmark(int* __restrict__ pP, int* __restrict__ pT,
                           unsigned char* __restrict__ flagP8,
                           unsigned char* __restrict__ flagT8) {
    int n = blockIdx.x * blockDim.x + threadIdx.x;
    if (n >= NTOT) return;
    int a = pP[n];
    int b = pT[n];
    bool fp = a >= 0;
    bool ft = b >= 0;
    if (fp) {
        int r = a, pr;
        while ((pr = pP[r]) != r) r = pr;
        if (a != r) pP[n] = r;
        if (!ft) flagP8[r] = 1;   // same-value races benign, no RMW
    }
    if (ft) {
        int r = b, pr;
        while ((pr = pT[r]) != r) r = pr;
        if (b != r) pT[n] = r;
        if (!fp) flagT8[r] = 1;
    }
}

// ---------- kernel 4: loss + mask blend + per-block partial (deterministic) ----------

__device__ __forceinline__ float softplusf(float z) {
    return fmaxf(z, 0.0f) + log1pf(expf(-fabsf(z)));
}

__device__ __forceinline__ float block_reduce_sum(float v, float* smem4) {
    for (int off = 32; off > 0; off >>= 1) v += __shfl_down(v, off, 64);
    int lane = threadIdx.x & 63, wid = threadIdx.x >> 6;
    if (lane == 0) smem4[wid] = v;
    __syncthreads();
    return smem4[0] + smem4[1] + smem4[2] + smem4[3];
}

__global__ void k_gather(const float* __restrict__ preds, const float* __restrict__ targets,
                         const int* __restrict__ pP, const int* __restrict__ pT,
                         const unsigned char* __restrict__ flagP8,
                         const unsigned char* __restrict__ flagT8,
                         float* __restrict__ partial) {
    int n = blockIdx.x * blockDim.x + threadIdx.x;
    float contrib = 0.0f;
    if (n < NTOT) {
        float x = preds[n];
        float t = targets[n];
        float loss = t * softplusf(-x) + (1.0f - t) * softplusf(x);
        int a = pP[n];   // final root after k_flatmark compression
        int b = pT[n];
        float m = 0.0f;
        if (b >= 0 && flagT8[b]) m += 0.5f;   // BETA * neg
        if (a >= 0 && flagP8[a]) m += 0.5f;   // (1-BETA) * pos
        contrib = (0.5f + 0.5f * m) * loss;   // (1-a)L + a*m*L, a=0.5
    }
    __shared__ float smem4[4];
    float s = block_reduce_sum(contrib, smem4);
    if (threadIdx.x == 0) partial[blockIdx.x] = s;
}

__global__ void k_final(const float* __restrict__ partial, float* __restrict__ out) {
    float s = 0.0f;
    for (int i = threadIdx.x; i < NBLK; i += 256) s += partial[i];
    __shared__ float smem4[4];
    float tot = block_reduce_sum(s, smem4);
    if (threadIdx.x == 0) out[0] = tot / (float)NTOT;
}

// ---------- launch ----------

extern "C" void kernel_launch(void* const* d_in, const int* in_sizes, int n_in,
                              void* d_out, int out_size, void* d_ws, size_t ws_size,
                              hipStream_t stream) {
    const float* preds = (const float*)d_in[0];
    const float* targets = (const float*)d_in[1];

    int* pP = (int*)d_ws;                              // 8 MB
    int* pT = pP + NTOT;                               // 8 MB
    unsigned char* flagP8 = (unsigned char*)(pT + NTOT);  // 2 MB
    unsigned char* flagT8 = flagP8 + NTOT;                // 2 MB (contiguous with flagP8)
    float* partial = (float*)(flagT8 + NTOT);             // 32 KB
    float* out = (float*)d_out;

    const int block = 256;

    k_local<<<2 * NTILES, block, 0, stream>>>(preds, targets, pP, pT,
                                              (unsigned long long*)flagP8);
    k_border<<<(2 * BPF + block - 1) / block, block, 0, stream>>>(pP, pT);
    k_flatmark<<<(NTOT + block - 1) / block, block, 0, stream>>>(pP, pT, flagP8, flagT8);
    k_gather<<<(NTOT + block - 1) / block, block, 0, stream>>>(preds, targets, pP, pT, flagP8, flagT8, partial);
    k_final<<<1, 256, 0, stream>>>(partial, out);
}